// Round 2
// baseline (322.769 us; speedup 1.0000x reference)
//
#include <hip/hip_runtime.h>

#define BSZ   32
#define SEQ   64
#define HID   256
#define G4    1024
#define NSTEP 64

typedef unsigned long long u64;
typedef unsigned int       u32;

__device__ __forceinline__ float sigmoidf_(float v) { return 1.f / (1.f + __expf(-v)); }

// ---------------------------------------------------------------------------
// Kernel 1: context[b,j] = sum_s softmax_s(x @ Wa_x)[b,s,j] * x[b,s,j]
// (ht/ct/ba terms are constant along the softmax axis -> cancel exactly.)
// grid: 32 b * 8 jt = 256 blocks; block: 256 threads = (j in 32) x (so in 8)
// ---------------------------------------------------------------------------
__global__ __launch_bounds__(256) void k_context(
    const float* __restrict__ x, const float* __restrict__ Wa,
    float* __restrict__ ctx)
{
  const int b   = blockIdx.x >> 3;
  const int jt  = blockIdx.x & 7;
  const int j   = threadIdx.x >> 3;
  const int so  = threadIdx.x & 7;
  const int jch = jt * 32 + j;
  const float* xb = x + (size_t)b * SEQ * HID;

  float acc[8];
#pragma unroll
  for (int i = 0; i < 8; ++i) acc[i] = 0.f;

  for (int k4 = 0; k4 < HID / 4; ++k4) {
    float4 xv[8];
#pragma unroll
    for (int ss = 0; ss < 8; ++ss)
      xv[ss] = *(const float4*)(xb + (so * 8 + ss) * HID + k4 * 4);
    const float wa0 = Wa[(k4 * 4 + 0) * HID + jch];
    const float wa1 = Wa[(k4 * 4 + 1) * HID + jch];
    const float wa2 = Wa[(k4 * 4 + 2) * HID + jch];
    const float wa3 = Wa[(k4 * 4 + 3) * HID + jch];
#pragma unroll
    for (int ss = 0; ss < 8; ++ss) {
      acc[ss] += xv[ss].x * wa0;
      acc[ss] += xv[ss].y * wa1;
      acc[ss] += xv[ss].z * wa2;
      acc[ss] += xv[ss].w * wa3;
    }
  }

  float m = acc[0];
#pragma unroll
  for (int ss = 1; ss < 8; ++ss) m = fmaxf(m, acc[ss]);
  m = fmaxf(m, __shfl_xor(m, 1));
  m = fmaxf(m, __shfl_xor(m, 2));
  m = fmaxf(m, __shfl_xor(m, 4));

  float e[8], s_ = 0.f;
#pragma unroll
  for (int ss = 0; ss < 8; ++ss) { e[ss] = __expf(acc[ss] - m); s_ += e[ss]; }
  s_ += __shfl_xor(s_, 1);
  s_ += __shfl_xor(s_, 2);
  s_ += __shfl_xor(s_, 4);
  const float inv = 1.f / s_;

  float cx = 0.f;
#pragma unroll
  for (int ss = 0; ss < 8; ++ss)
    cx += e[ss] * xb[(so * 8 + ss) * HID + jch];
  cx *= inv;
  cx += __shfl_xor(cx, 1);
  cx += __shfl_xor(cx, 2);
  cx += __shfl_xor(cx, 4);

  if (so == 0) ctx[b * HID + jch] = cx;
}

// ---------------------------------------------------------------------------
// Kernel 2: 64 sequential LSTM steps. grid: 32 b * 8 q = 256 blocks.
// Block (b,q) owns hidden j in [q*32, q*32+32) = 128 Wh columns.
// Lane map (per wave wv): lane = (gate*2 + p)*8 + kq
//   gate in 0..3, p in 0..1, kq in 0..7 (k-slice kq*32..+32)
//   thread's 4 cols = gate*HID + q*32 + wv*8 + p*4 .. +3
// Wh slice pinned in VGPRs (wr[128], asm-pinned against rematerialization).
// After kq shfl-reduce, shfl_xor(16/32) gathers i,f,g,o in gate==0 lanes ->
// pointwise + tagged publish with NO extra LDS round / syncthreads.
// ht exchange: tagged 8B words {f32,hi | tag,lo} in d_ws, relaxed agent-scope
// atomics, double-buffered by parity. 0xAA poison never matches tags 1..64.
// ---------------------------------------------------------------------------
__global__ __launch_bounds__(256, 1) void k_recurrent(
    const float* __restrict__ Wi, const float* __restrict__ Wh,
    const float* __restrict__ bias, const float* __restrict__ Wf,
    const float* __restrict__ bf, const float* __restrict__ ctx,
    u64* __restrict__ tht, float* __restrict__ out)
{
  const int b    = blockIdx.x >> 3;
  const int q    = blockIdx.x & 7;
  const int tid  = threadIdx.x;
  const int lane = tid & 63;
  const int wv   = tid >> 6;        // 0..3
  const int kq   = lane & 7;        // k-slice
  const int cgp  = lane >> 3;       // 0..7
  const int gate = cgp >> 1;        // 0..3
  const int p    = cgp & 1;         // 0..1
  const int j0   = q * 32 + wv * 8 + p * 4;   // hidden quad (global j)
  const int col0 = gate * HID + j0;           // column in 4H

  __shared__ float hs[2][8][36];    // [parity][kq][32 + pad] (36 = conflict-free f4)
  __shared__ float red[4];

  // ---- Wh slice -> VGPRs, pinned against rematerialization ----
  float wr[128];
#pragma unroll
  for (int kk = 0; kk < 32; ++kk) {
    const float4 w4 = *(const float4*)(Wh + (size_t)(kq * 32 + kk) * G4 + col0);
    wr[kk * 4 + 0] = w4.x; wr[kk * 4 + 1] = w4.y;
    wr[kk * 4 + 2] = w4.z; wr[kk * 4 + 3] = w4.w;
  }
#pragma unroll
  for (int i = 0; i < 128; i += 4)
    asm volatile("" : "+v"(wr[i]), "+v"(wr[i + 1]), "+v"(wr[i + 2]), "+v"(wr[i + 3]));

  // ---- stage context, compute Gc = ctx@Wi + bias (seeded in kq==0) ----
  hs[0][tid >> 5][tid & 31] = ctx[b * HID + tid];
  __syncthreads();

  float gx = 0.f, gy = 0.f, gz = 0.f, gw = 0.f;
#pragma unroll 4
  for (int kk = 0; kk < 32; ++kk) {
    const float4 w4 = *(const float4*)(Wi + (size_t)(kq * 32 + kk) * G4 + col0);
    const float h = hs[0][kq][kk];
    gx += h * w4.x; gy += h * w4.y; gz += h * w4.z; gw += h * w4.w;
  }
#pragma unroll
  for (int mk = 1; mk < 8; mk <<= 1) {
    gx += __shfl_xor(gx, mk); gy += __shfl_xor(gy, mk);
    gz += __shfl_xor(gz, mk); gw += __shfl_xor(gw, mk);
  }
  float gcx, gcy, gcz, gcw;
  if (kq == 0) {
    const float4 bb = *(const float4*)(bias + col0);
    gcx = gx + bb.x; gcy = gy + bb.y; gcz = gz + bb.z; gcw = gw + bb.w;
  } else {
    gcx = gcy = gcz = gcw = 0.f;   // only kq==0 seeds the step reduction
  }
  __syncthreads();
  hs[0][tid >> 5][tid & 31] = 0.f;  // h0 = 0
  float c0 = 0.f, c1 = 0.f, c2 = 0.f, c3 = 0.f;  // c state (gate==0,kq==0 lanes)
  __syncthreads();

  for (int t = 0; t < NSTEP; ++t) {
    const int rb = t & 1;
    const int wb = (t + 1) & 1;

    if (t > 0) {
      const u64* pp = tht + (size_t)rb * BSZ * HID + (size_t)b * HID + tid;
      u64 pk;
      do {
        pk = __hip_atomic_load(pp, __ATOMIC_RELAXED, __HIP_MEMORY_SCOPE_AGENT);
      } while ((u32)pk != (u32)t);
      hs[rb][tid >> 5][tid & 31] = __uint_as_float((u32)(pk >> 32));
      __syncthreads();
    }

    // gates partial: 4 cols x 32 k, Wh from pinned regs
    float ax = gcx, ay = gcy, az = gcz, aw = gcw;
#pragma unroll
    for (int k4 = 0; k4 < 8; ++k4) {
      const float4 h4 = *(const float4*)&hs[rb][kq][k4 * 4];
      const int bs0 = k4 * 16;
      ax += h4.x * wr[bs0 +  0]; ay += h4.x * wr[bs0 +  1];
      az += h4.x * wr[bs0 +  2]; aw += h4.x * wr[bs0 +  3];
      ax += h4.y * wr[bs0 +  4]; ay += h4.y * wr[bs0 +  5];
      az += h4.y * wr[bs0 +  6]; aw += h4.y * wr[bs0 +  7];
      ax += h4.z * wr[bs0 +  8]; ay += h4.z * wr[bs0 +  9];
      az += h4.z * wr[bs0 + 10]; aw += h4.z * wr[bs0 + 11];
      ax += h4.w * wr[bs0 + 12]; ay += h4.w * wr[bs0 + 13];
      az += h4.w * wr[bs0 + 14]; aw += h4.w * wr[bs0 + 15];
    }
    // reduce over the 8 kq partners
#pragma unroll
    for (int mk = 1; mk < 8; mk <<= 1) {
      ax += __shfl_xor(ax, mk); ay += __shfl_xor(ay, mk);
      az += __shfl_xor(az, mk); aw += __shfl_xor(aw, mk);
    }
    // gather the 4 gates across lane bits 4,5 (gate = lane>>4 within wave)
    const float fx = __shfl_xor(ax, 16), fy = __shfl_xor(ay, 16),
                fz = __shfl_xor(az, 16), fw = __shfl_xor(aw, 16);
    const float gx2 = __shfl_xor(ax, 32), gy2 = __shfl_xor(ay, 32),
                gz2 = __shfl_xor(az, 32), gw2 = __shfl_xor(aw, 32);
    const float ox = __shfl_xor(fx, 32), oy = __shfl_xor(fy, 32),
                oz = __shfl_xor(fz, 32), ow = __shfl_xor(fw, 32);

    if (gate == 0 && kq == 0) {
      // for gate==0 lanes: own=i, ^16=f, ^32=g, ^48=o
      const float i0 = sigmoidf_(ax),  i1 = sigmoidf_(ay),
                  i2 = sigmoidf_(az),  i3 = sigmoidf_(aw);
      const float f0 = sigmoidf_(fx),  f1 = sigmoidf_(fy),
                  f2 = sigmoidf_(fz),  f3 = sigmoidf_(fw);
      const float g0 = tanhf(gx2),     g1 = tanhf(gy2),
                  g2 = tanhf(gz2),     g3 = tanhf(gw2);
      const float o0 = sigmoidf_(ox),  o1 = sigmoidf_(oy),
                  o2 = sigmoidf_(oz),  o3 = sigmoidf_(ow);
      c0 = f0 * c0 + i0 * g0;  c1 = f1 * c1 + i1 * g1;
      c2 = f2 * c2 + i2 * g2;  c3 = f3 * c3 + i3 * g3;
      const float h0v = o0 * tanhf(c0), h1v = o1 * tanhf(c1);
      const float h2v = o2 * tanhf(c2), h3v = o3 * tanhf(c3);
      u64* dst = tht + (size_t)wb * BSZ * HID + (size_t)b * HID + j0;
      const u64 tg = (u64)(u32)(t + 1);
      __hip_atomic_store(dst + 0, (((u64)__float_as_uint(h0v)) << 32) | tg,
                         __ATOMIC_RELAXED, __HIP_MEMORY_SCOPE_AGENT);
      __hip_atomic_store(dst + 1, (((u64)__float_as_uint(h1v)) << 32) | tg,
                         __ATOMIC_RELAXED, __HIP_MEMORY_SCOPE_AGENT);
      __hip_atomic_store(dst + 2, (((u64)__float_as_uint(h2v)) << 32) | tg,
                         __ATOMIC_RELAXED, __HIP_MEMORY_SCOPE_AGENT);
      __hip_atomic_store(dst + 3, (((u64)__float_as_uint(h3v)) << 32) | tg,
                         __ATOMIC_RELAXED, __HIP_MEMORY_SCOPE_AGENT);
    }
    // no trailing barrier: next staging targets the other parity buffer, and
    // the sync at step t+1 orders step-t reads before t+2 overwrites.
  }

  // ---- epilogue: out[b] = ht64 @ Wf + bf (q==0 sibling only) ----
  if (q == 0) {
    const u64* pp = tht + /*parity 0*/ (size_t)b * HID + tid;
    u64 pk;
    do {
      pk = __hip_atomic_load(pp, __ATOMIC_RELAXED, __HIP_MEMORY_SCOPE_AGENT);
    } while ((u32)pk != (u32)NSTEP);
    const float hv = __uint_as_float((u32)(pk >> 32));
    float prod = hv * Wf[tid];
#pragma unroll
    for (int mk = 1; mk < 64; mk <<= 1) prod += __shfl_xor(prod, mk);
    if (lane == 0) red[wv] = prod;
    __syncthreads();
    if (tid == 0) out[b] = red[0] + red[1] + red[2] + red[3] + bf[0];
  }
}

// ---------------------------------------------------------------------------
extern "C" void kernel_launch(void* const* d_in, const int* in_sizes, int n_in,
                              void* d_out, int out_size, void* d_ws, size_t ws_size,
                              hipStream_t stream)
{
  const float* x  = (const float*)d_in[0];
  const float* Wa = (const float*)d_in[1];
  // d_in[2] = ba: unused — constant along softmax axis, cancels exactly
  const float* Wi = (const float*)d_in[3];
  const float* Wh = (const float*)d_in[4];
  const float* bi = (const float*)d_in[5];
  const float* Wf = (const float*)d_in[6];
  const float* bf = (const float*)d_in[7];
  float* out = (float*)d_out;

  // ws layout: [0,32KB) fp32 context; [32KB, 32KB+128KB) tagged ht (2 bufs)
  float* ctx = (float*)d_ws;
  u64*   tht = (u64*)((char*)d_ws + 32 * 1024);

  hipLaunchKernelGGL(k_context,   dim3(BSZ * 8), dim3(256), 0, stream, x, Wa, ctx);
  hipLaunchKernelGGL(k_recurrent, dim3(BSZ * 8), dim3(256), 0, stream,
                     Wi, Wh, bi, Wf, bf, ctx, tht, out);
}